// Round 4
// baseline (38996.939 us; speedup 1.0000x reference)
//
#include <hip/hip_runtime.h>

// VQ nearest-codebook: x [262144,256] f32, emb [1024,256] f32
// out = concat(z_q [262144*256] f32, min_indices [262144] written as f32)
//
// Round 4: bf16 MFMA approximate scorer (error sigma ~3e-5) + sticky near-tie
// flagging at THR=7e-4; flagged tokens re-scored with the R3-verified bitwise
// numpy-f32 chain (pairwise rowsq + ascending-k single-acc fmac dot +
// fl(fl(A+B)-2dot)), first-occurrence argmin.

constexpr int N_E   = 1024;
constexpr int E_DIM = 256;
constexpr int N_TOK = 262144;
constexpr float THR = 7e-4f;

typedef __attribute__((ext_vector_type(8))) short short8;
typedef __attribute__((ext_vector_type(4))) float f32x4;

// ---------- bitwise-verified helpers from R3 ----------
__device__ __forceinline__ float sqf(float v) {
    float p = v * v;
    asm volatile("" : "+v"(p));
    return p;
}
// numpy pairwise block (AVX512 npyv DAG) over squares of b[0..n), 64<=n<=128
__device__ __forceinline__ float pwb(const float* b, int n) {
    float U[8];
#pragma unroll
    for (int L = 0; L < 8; ++L) {
        float TL  = (sqf(b[L])     + sqf(b[16 + L])) + (sqf(b[32 + L]) + sqf(b[48 + L]));
        float TL8 = (sqf(b[8 + L]) + sqf(b[24 + L])) + (sqf(b[40 + L]) + sqf(b[56 + L]));
        U[L] = TL + TL8;
    }
    float V0 = U[0] + U[4], V1 = U[1] + U[5], V2 = U[2] + U[6], V3 = U[3] + U[7];
    float res = (V0 + V2) + (V1 + V3);
    for (int i = 64; i < n; ++i) res += sqf(b[i]);
    return res;
}
__device__ __forceinline__ float rowsq_exact(const float* r) {
    return sqf(r[0]) + (pwb(r + 1, 120) + (pwb(r + 121, 64) + pwb(r + 185, 71)));
}

__device__ __forceinline__ unsigned short f2bf(float f) {  // RNE f32->bf16
    union { float f; unsigned u; } v; v.f = f;
    unsigned r = (v.u + 0x7FFF + ((v.u >> 16) & 1)) >> 16;
    return (unsigned short)r;
}

// ---------- prep: exact ||e_k||^2 (bitwise rowsq) ----------
__global__ __launch_bounds__(64) void rowsq_kernel(const float* __restrict__ src,
                                                   float* __restrict__ dst) {
    __shared__ float rs[32][257];
    const int rowBase = blockIdx.x * 32;
    const int tid = threadIdx.x;
    const float4* s4 = reinterpret_cast<const float4*>(src);
    for (int i = tid; i < 32 * 64; i += 64) {
        int rr = i >> 6, c4 = i & 63;
        float4 v = s4[(size_t)(rowBase + rr) * 64 + c4];
        rs[rr][c4 * 4 + 0] = v.x;
        rs[rr][c4 * 4 + 1] = v.y;
        rs[rr][c4 * 4 + 2] = v.z;
        rs[rr][c4 * 4 + 3] = v.w;
    }
    __syncthreads();
    if (tid < 32) dst[rowBase + tid] = rowsq_exact(rs[tid]);
}

// ---------- prep: emb -> bf16 fragment-order [nt][kc][lane][8] ----------
__global__ __launch_bounds__(256) void eprep_kernel(const float* __restrict__ emb,
                                                    short8* __restrict__ eb,
                                                    int* __restrict__ cnt) {
    int gid = blockIdx.x * 256 + threadIdx.x;   // 32768 total
    if (gid == 0) *cnt = 0;                     // re-zero each launch (graph replays)
    int lane = gid & 63;
    int kc   = (gid >> 6) & 7;
    int nt   = gid >> 9;
    int cand = nt * 16 + (lane & 15);
    int k0   = kc * 32 + (lane >> 4) * 8;
    const float4* e4 = reinterpret_cast<const float4*>(emb);
    float4 a = e4[(size_t)cand * 64 + k0 / 4];
    float4 b = e4[(size_t)cand * 64 + k0 / 4 + 1];
    short8 o;
    o[0] = (short)f2bf(a.x); o[1] = (short)f2bf(a.y);
    o[2] = (short)f2bf(a.z); o[3] = (short)f2bf(a.w);
    o[4] = (short)f2bf(b.x); o[5] = (short)f2bf(b.y);
    o[6] = (short)f2bf(b.z); o[7] = (short)f2bf(b.w);
    eb[gid] = o;
}

// ---------- MFMA scorer: 256 thr = 4 waves, 64 tokens/wave ----------
__global__ __launch_bounds__(256, 2) void score_kernel(const float* __restrict__ x,
                                                       const float* __restrict__ emb,
                                                       const short8* __restrict__ eb,
                                                       const float* __restrict__ B,
                                                       float* __restrict__ zq,
                                                       float* __restrict__ outIdx,
                                                       int* __restrict__ cnt,
                                                       int* __restrict__ list,
                                                       int listCap) {
    __shared__ int fidx[256];
    const int tid = threadIdx.x;
    const int wv  = tid >> 6;
    const int l   = tid & 63;
    const int col = l & 15;
    const int tokW = blockIdx.x * 256 + wv * 64;
    const float4* x4 = reinterpret_cast<const float4*>(x);

    // A-frags: lane l holds token row (l&15), k = (l>>4)*8 + j  (16x16x32 bf16)
    short8 xf[4][8];
#pragma unroll
    for (int mt = 0; mt < 4; ++mt) {
        int row = tokW + mt * 16 + col;
#pragma unroll
        for (int kc = 0; kc < 8; ++kc) {
            const float4* p = x4 + (size_t)row * 64 + kc * 8 + (l >> 4) * 2;
            float4 a = p[0], b = p[1];
            short8 f;
            f[0] = (short)f2bf(a.x); f[1] = (short)f2bf(a.y);
            f[2] = (short)f2bf(a.z); f[3] = (short)f2bf(a.w);
            f[4] = (short)f2bf(b.x); f[5] = (short)f2bf(b.y);
            f[6] = (short)f2bf(b.z); f[7] = (short)f2bf(b.w);
            xf[mt][kc] = f;
        }
    }

    float m1[16];
    int   i1[16];
    unsigned flags = 0;
#pragma unroll
    for (int t = 0; t < 16; ++t) { m1[t] = 3.4e38f; i1[t] = 0; }

    for (int nt = 0; nt < 64; ++nt) {
        float Bv = B[nt * 16 + col];
        const short8* ep = eb + nt * 512 + l;
        f32x4 acc0 = {0.f, 0.f, 0.f, 0.f}, acc1 = acc0, acc2 = acc0, acc3 = acc0;
#pragma unroll
        for (int kc = 0; kc < 8; ++kc) {
            short8 ef = ep[kc * 64];   // B-frag: col=l&15, k=(l>>4)*8+j
            acc0 = __builtin_amdgcn_mfma_f32_16x16x32_bf16(xf[0][kc], ef, acc0, 0, 0, 0);
            acc1 = __builtin_amdgcn_mfma_f32_16x16x32_bf16(xf[1][kc], ef, acc1, 0, 0, 0);
            acc2 = __builtin_amdgcn_mfma_f32_16x16x32_bf16(xf[2][kc], ef, acc2, 0, 0, 0);
            acc3 = __builtin_amdgcn_mfma_f32_16x16x32_bf16(xf[3][kc], ef, acc3, 0, 0, 0);
        }
        int idx = nt * 16 + col;
#pragma unroll
        for (int mt = 0; mt < 4; ++mt) {
            f32x4 acc = (mt == 0) ? acc0 : (mt == 1) ? acc1 : (mt == 2) ? acc2 : acc3;
#pragma unroll
            for (int r = 0; r < 4; ++r) {
                int t = mt * 4 + r;
                float s = Bv - 2.0f * acc[r];
                float prev = m1[t];
                if (s < prev) {
                    if (prev - s <= THR) flags |= 1u << t;   // old min is a near-tie
                    m1[t] = s; i1[t] = idx;                  // idx ascending -> first occurrence
                } else if (s - prev <= THR) {
                    flags |= 1u << t;
                }
            }
        }
    }

    // merge across the 16 lanes sharing a token (xor 1,2,4,8)
#pragma unroll
    for (int off = 1; off <= 8; off <<= 1) {
        unsigned add = (unsigned)__shfl_xor((int)flags, off, 64);
#pragma unroll
        for (int t = 0; t < 16; ++t) {
            float om = __shfl_xor(m1[t], off, 64);
            int   oi = __shfl_xor(i1[t], off, 64);
            if (fabsf(om - m1[t]) <= THR) add |= 1u << t;
            if (om < m1[t] || (om == m1[t] && oi < i1[t])) { m1[t] = om; i1[t] = oi; }
        }
        flags |= add;
    }

    if (col == 0) {   // 4 leader lanes per wave, each owns (l>>4) row-group
        int g = l >> 4;
#pragma unroll
        for (int mt = 0; mt < 4; ++mt)
#pragma unroll
            for (int r = 0; r < 4; ++r) {
                int t = mt * 4 + r;
                int token = tokW + mt * 16 + g * 4 + r;
                outIdx[token] = (float)i1[t];
                fidx[wv * 64 + mt * 16 + g * 4 + r] = i1[t];
                if ((flags >> t) & 1u) {
                    int p = atomicAdd(cnt, 1);
                    if (p < listCap) list[p] = token;
                }
            }
    }
    __syncthreads();

    const float4* e4 = reinterpret_cast<const float4*>(emb);
    float4* zq4 = reinterpret_cast<float4*>(zq);
#pragma unroll
    for (int it = 0; it < 64; ++it) {
        int flat = it * 256 + tid;
        int t = flat >> 6, c = flat & 63;
        zq4[((size_t)blockIdx.x * 256 + t) * 64 + c] = e4[(size_t)fidx[t] * 64 + c];
    }
}

// ---------- exact recheck of flagged tokens (bitwise np chain) ----------
__global__ __launch_bounds__(256) void recheck_kernel(const float* __restrict__ x,
                                                      const float* __restrict__ emb,
                                                      const float* __restrict__ B,
                                                      float* __restrict__ zq,
                                                      float* __restrict__ outIdx,
                                                      const int* __restrict__ cnt,
                                                      const int* __restrict__ list,
                                                      int listCap) {
    __shared__ float xs[E_DIM];
    __shared__ float As;
    __shared__ float rmin[256];
    __shared__ int   ridx[256];

    const int tid = threadIdx.x;
    const float4* x4 = reinterpret_cast<const float4*>(x);
    const float4* e4 = reinterpret_cast<const float4*>(emb);
    float4* zq4 = reinterpret_cast<float4*>(zq);

    int n = *cnt;
    bool overflow = n > listCap;           // ws too small: fall back to all tokens
    int total = overflow ? N_TOK : n;

    for (int w = blockIdx.x; w < total; w += gridDim.x) {
        int tok = overflow ? w : list[w];
        if (tid < 64) {
            float4 v = x4[(size_t)tok * 64 + tid];
            xs[tid * 4 + 0] = v.x; xs[tid * 4 + 1] = v.y;
            xs[tid * 4 + 2] = v.z; xs[tid * 4 + 3] = v.w;
        }
        __syncthreads();
        if (tid == 0) As = rowsq_exact(xs);
        __syncthreads();

        // 4 cands/thread: c = j*256 + tid; ascending-k single-acc fmac (bitwise)
        float acc[4] = {0.f, 0.f, 0.f, 0.f};
        for (int d4 = 0; d4 < 64; ++d4) {
            float x0 = xs[d4 * 4 + 0], x1 = xs[d4 * 4 + 1];
            float x2 = xs[d4 * 4 + 2], x3 = xs[d4 * 4 + 3];
#pragma unroll
            for (int j = 0; j < 4; ++j) {
                float4 e = e4[(size_t)(j * 256 + tid) * 64 + d4];
                acc[j] += x0 * e.x;
                acc[j] += x1 * e.y;
                acc[j] += x2 * e.z;
                acc[j] += x3 * e.w;
            }
        }
        float bm = 3.4e38f;
        int   bi = 0;
#pragma unroll
        for (int j = 0; j < 4; ++j) {
            int c = j * 256 + tid;
            float t = As + B[c];             // fl(A+B)
            float s = t - 2.0f * acc[j];     // fl(t - 2*dot)
            if (s < bm) { bm = s; bi = c; }  // c ascending -> first occurrence
        }
        rmin[tid] = bm; ridx[tid] = bi;
        __syncthreads();
        for (int s = 128; s > 0; s >>= 1) {
            if (tid < s) {
                float o  = rmin[tid + s];
                int   oi = ridx[tid + s];
                if (o < rmin[tid] || (o == rmin[tid] && oi < ridx[tid])) {
                    rmin[tid] = o; ridx[tid] = oi;
                }
            }
            __syncthreads();
        }
        int bk = ridx[0];
        if (tid == 0) outIdx[tok] = (float)bk;
        if (tid < 64) zq4[(size_t)tok * 64 + tid] = e4[(size_t)bk * 64 + tid];
        __syncthreads();   // protect xs/As before next iteration
    }
}

extern "C" void kernel_launch(void* const* d_in, const int* in_sizes, int n_in,
                              void* d_out, int out_size, void* d_ws, size_t ws_size,
                              hipStream_t stream) {
    const float* x   = (const float*)d_in[0];
    const float* emb = (const float*)d_in[1];
    float* out    = (float*)d_out;
    float* zq     = out;
    float* outIdx = out + (size_t)N_TOK * E_DIM;

    char* ws = (char*)d_ws;
    int*    cnt  = (int*)ws;                    // @0
    float*  B    = (float*)(ws + 4096);         // 4 KB
    short8* eb   = (short8*)(ws + 8192);        // 512 KB fragment-order bf16 emb
    int*    list = (int*)(ws + 8192 + 524288);  // flagged-token list
    long avail = (long)ws_size - (8192 + 524288);
    int listCap = avail > 0 ? (int)(avail / 4) : 0;
    if (listCap > N_TOK) listCap = N_TOK;

    eprep_kernel<<<128, 256, 0, stream>>>(emb, eb, cnt);
    rowsq_kernel<<<N_E / 32, 64, 0, stream>>>(emb, B);
    score_kernel<<<N_TOK / 256, 256, 0, stream>>>(x, emb, eb, B, zq, outIdx, cnt, list, listCap);
    recheck_kernel<<<8192, 256, 0, stream>>>(x, emb, B, zq, outIdx, cnt, list, listCap);
}

// Round 5
// 5200.407 us; speedup vs baseline: 7.4988x; 7.4988x over previous
//
#include <hip/hip_runtime.h>

// VQ nearest-codebook: x [262144,256] f32, emb [1024,256] f32
// out = concat(z_q [262144*256] f32, min_indices [262144] written as f32)
//
// Round 5: bf16 MFMA scorer flags near-ties (THR) by writing idx+1024 into
// outIdx; recheck_kernel scans outIdx, batches flagged tokens (16/sub-batch)
// per block and re-scores them with the R3/R4-verified bitwise numpy-f32 chain
// (pairwise rowsq + ascending-k single-acc fmac dot + fl(fl(A+B)-2dot)).
// No ws list, no atomics -> no overflow path.

constexpr int N_E   = 1024;
constexpr int E_DIM = 256;
constexpr int N_TOK = 262144;
constexpr float THR = 7e-4f;

typedef __attribute__((ext_vector_type(8))) short short8;
typedef __attribute__((ext_vector_type(4))) float f32x4;

// ---------- bitwise-verified helpers (R3/R4) ----------
__device__ __forceinline__ float sqf(float v) {
    float p = v * v;
    asm volatile("" : "+v"(p));
    return p;
}
__device__ __forceinline__ float pwb(const float* b, int n) {
    float U[8];
#pragma unroll
    for (int L = 0; L < 8; ++L) {
        float TL  = (sqf(b[L])     + sqf(b[16 + L])) + (sqf(b[32 + L]) + sqf(b[48 + L]));
        float TL8 = (sqf(b[8 + L]) + sqf(b[24 + L])) + (sqf(b[40 + L]) + sqf(b[56 + L]));
        U[L] = TL + TL8;
    }
    float V0 = U[0] + U[4], V1 = U[1] + U[5], V2 = U[2] + U[6], V3 = U[3] + U[7];
    float res = (V0 + V2) + (V1 + V3);
    for (int i = 64; i < n; ++i) res += sqf(b[i]);
    return res;
}
__device__ __forceinline__ float rowsq_exact(const float* r) {
    return sqf(r[0]) + (pwb(r + 1, 120) + (pwb(r + 121, 64) + pwb(r + 185, 71)));
}
__device__ __forceinline__ unsigned short f2bf(float f) {
    union { float f; unsigned u; } v; v.f = f;
    unsigned r = (v.u + 0x7FFF + ((v.u >> 16) & 1)) >> 16;
    return (unsigned short)r;
}

// ---------- prep: exact ||e_k||^2 ----------
__global__ __launch_bounds__(64) void rowsq_kernel(const float* __restrict__ src,
                                                   float* __restrict__ dst) {
    __shared__ float rs[32][257];
    const int rowBase = blockIdx.x * 32;
    const int tid = threadIdx.x;
    const float4* s4 = reinterpret_cast<const float4*>(src);
    for (int i = tid; i < 32 * 64; i += 64) {
        int rr = i >> 6, c4 = i & 63;
        float4 v = s4[(size_t)(rowBase + rr) * 64 + c4];
        rs[rr][c4 * 4 + 0] = v.x;
        rs[rr][c4 * 4 + 1] = v.y;
        rs[rr][c4 * 4 + 2] = v.z;
        rs[rr][c4 * 4 + 3] = v.w;
    }
    __syncthreads();
    if (tid < 32) dst[rowBase + tid] = rowsq_exact(rs[tid]);
}

// ---------- prep: emb -> bf16 fragment-order [nt][kc][lane] ----------
__global__ __launch_bounds__(256) void eprep_kernel(const float* __restrict__ emb,
                                                    short8* __restrict__ eb) {
    int gid = blockIdx.x * 256 + threadIdx.x;   // 32768
    int lane = gid & 63;
    int kc   = (gid >> 6) & 7;
    int nt   = gid >> 9;
    int cand = nt * 16 + (lane & 15);
    int k0   = kc * 32 + (lane >> 4) * 8;
    const float4* e4 = reinterpret_cast<const float4*>(emb);
    float4 a = e4[(size_t)cand * 64 + k0 / 4];
    float4 b = e4[(size_t)cand * 64 + k0 / 4 + 1];
    short8 o;
    o[0] = (short)f2bf(a.x); o[1] = (short)f2bf(a.y);
    o[2] = (short)f2bf(a.z); o[3] = (short)f2bf(a.w);
    o[4] = (short)f2bf(b.x); o[5] = (short)f2bf(b.y);
    o[6] = (short)f2bf(b.z); o[7] = (short)f2bf(b.w);
    eb[gid] = o;
}

// ---------- MFMA scorer (layout verified in R4) ----------
__global__ __launch_bounds__(256, 2) void score_kernel(const float* __restrict__ x,
                                                       const float* __restrict__ emb,
                                                       const short8* __restrict__ eb,
                                                       const float* __restrict__ B,
                                                       float* __restrict__ zq,
                                                       float* __restrict__ outIdx) {
    __shared__ int fidx[256];
    const int tid = threadIdx.x;
    const int wv  = tid >> 6;
    const int l   = tid & 63;
    const int col = l & 15;
    const int tokW = blockIdx.x * 256 + wv * 64;
    const float4* x4 = reinterpret_cast<const float4*>(x);

    short8 xf[4][8];
#pragma unroll
    for (int mt = 0; mt < 4; ++mt) {
        int row = tokW + mt * 16 + col;
#pragma unroll
        for (int kc = 0; kc < 8; ++kc) {
            const float4* p = x4 + (size_t)row * 64 + kc * 8 + (l >> 4) * 2;
            float4 a = p[0], b = p[1];
            short8 f;
            f[0] = (short)f2bf(a.x); f[1] = (short)f2bf(a.y);
            f[2] = (short)f2bf(a.z); f[3] = (short)f2bf(a.w);
            f[4] = (short)f2bf(b.x); f[5] = (short)f2bf(b.y);
            f[6] = (short)f2bf(b.z); f[7] = (short)f2bf(b.w);
            xf[mt][kc] = f;
        }
    }

    float m1[16];
    int   i1[16];
    unsigned flags = 0;
#pragma unroll
    for (int t = 0; t < 16; ++t) { m1[t] = 3.4e38f; i1[t] = 0; }

    for (int nt = 0; nt < 64; ++nt) {
        float Bv = B[nt * 16 + col];
        const short8* ep = eb + nt * 512 + l;
        f32x4 acc0 = {0.f, 0.f, 0.f, 0.f}, acc1 = acc0, acc2 = acc0, acc3 = acc0;
#pragma unroll
        for (int kc = 0; kc < 8; ++kc) {
            short8 ef = ep[kc * 64];
            acc0 = __builtin_amdgcn_mfma_f32_16x16x32_bf16(xf[0][kc], ef, acc0, 0, 0, 0);
            acc1 = __builtin_amdgcn_mfma_f32_16x16x32_bf16(xf[1][kc], ef, acc1, 0, 0, 0);
            acc2 = __builtin_amdgcn_mfma_f32_16x16x32_bf16(xf[2][kc], ef, acc2, 0, 0, 0);
            acc3 = __builtin_amdgcn_mfma_f32_16x16x32_bf16(xf[3][kc], ef, acc3, 0, 0, 0);
        }
        int idx = nt * 16 + col;
#pragma unroll
        for (int mt = 0; mt < 4; ++mt) {
            f32x4 acc = (mt == 0) ? acc0 : (mt == 1) ? acc1 : (mt == 2) ? acc2 : acc3;
#pragma unroll
            for (int r = 0; r < 4; ++r) {
                int t = mt * 4 + r;
                float s = Bv - 2.0f * acc[r];
                if (fabsf(s - m1[t]) <= THR) flags |= 1u << t;  // sticky near-tie (sound)
                if (s < m1[t]) { m1[t] = s; i1[t] = idx; }
            }
        }
    }

#pragma unroll
    for (int off = 1; off <= 8; off <<= 1) {
        unsigned add = (unsigned)__shfl_xor((int)flags, off, 64);
#pragma unroll
        for (int t = 0; t < 16; ++t) {
            float om = __shfl_xor(m1[t], off, 64);
            int   oi = __shfl_xor(i1[t], off, 64);
            if (fabsf(om - m1[t]) <= THR) add |= 1u << t;
            if (om < m1[t] || (om == m1[t] && oi < i1[t])) { m1[t] = om; i1[t] = oi; }
        }
        flags |= add;
    }

    if (col == 0) {
        int g = l >> 4;
#pragma unroll
        for (int mt = 0; mt < 4; ++mt)
#pragma unroll
            for (int r = 0; r < 4; ++r) {
                int t = mt * 4 + r;
                int token = tokW + mt * 16 + g * 4 + r;
                int fl = (flags >> t) & 1u;
                outIdx[token] = (float)(i1[t] + (fl ? N_E : 0));  // flag marker
                fidx[wv * 64 + mt * 16 + g * 4 + r] = i1[t];
            }
    }
    __syncthreads();

    const float4* e4 = reinterpret_cast<const float4*>(emb);
    float4* zq4 = reinterpret_cast<float4*>(zq);
#pragma unroll
    for (int it = 0; it < 64; ++it) {
        int flat = it * 256 + tid;
        int t = flat >> 6, c = flat & 63;
        zq4[((size_t)blockIdx.x * 256 + t) * 64 + c] = e4[(size_t)fidx[t] * 64 + c];
    }
}

// ---------- batched exact recheck: 128 tokens scanned per block ----------
__global__ __launch_bounds__(256) void recheck_kernel(const float* __restrict__ x,
                                                      const float* __restrict__ emb,
                                                      const float* __restrict__ B,
                                                      float* __restrict__ zq,
                                                      float* __restrict__ outIdx) {
    __shared__ float xs[16][257];
    __shared__ float As[16];
    __shared__ int   toks[128];
    __shared__ int   kcount;
    __shared__ float wmin[4][16];
    __shared__ int   widx[4][16];
    __shared__ int   bidx[16];

    const int tid  = threadIdx.x;
    const int wv   = tid >> 6;
    const int l    = tid & 63;
    const int base = blockIdx.x * 128;
    const float4* x4 = reinterpret_cast<const float4*>(x);
    const float4* e4 = reinterpret_cast<const float4*>(emb);
    float4* zq4 = reinterpret_cast<float4*>(zq);

    if (tid == 0) kcount = 0;
    __syncthreads();
    if (tid < 128) {
        float v = outIdx[base + tid];
        if (v >= (float)N_E) {                // flagged
            int p = atomicAdd(&kcount, 1);    // LDS atomic; order-independent results
            toks[p] = base + tid;
        }
    }
    __syncthreads();
    const int k = kcount;

    for (int sb = 0; sb < k; sb += 16) {
        const int m = (k - sb < 16) ? (k - sb) : 16;
        // stage x rows (zeros for t >= m keeps loops static & safe)
        for (int i = tid; i < 16 * 64; i += 256) {
            int t = i >> 6, c4 = i & 63;
            float4 v = {0.f, 0.f, 0.f, 0.f};
            if (t < m) v = x4[(size_t)toks[sb + t] * 64 + c4];
            xs[t][c4 * 4 + 0] = v.x;
            xs[t][c4 * 4 + 1] = v.y;
            xs[t][c4 * 4 + 2] = v.z;
            xs[t][c4 * 4 + 3] = v.w;
        }
        __syncthreads();
        if (tid < 16) As[tid] = rowsq_exact(xs[tid]);
        __syncthreads();

        float m1[16];
        int   i1[16];
#pragma unroll
        for (int t = 0; t < 16; ++t) { m1[t] = 3.4e38f; i1[t] = 0; }

        for (int pass = 0; pass < 4; ++pass) {
            const int c = pass * 256 + tid;
            const float Bc = B[c];
            float acc[16];
#pragma unroll
            for (int t = 0; t < 16; ++t) acc[t] = 0.f;
            for (int ch = 0; ch < 16; ++ch) {
                float4 ea = e4[(size_t)c * 64 + ch * 4 + 0];
                float4 eb_ = e4[(size_t)c * 64 + ch * 4 + 1];
                float4 ec = e4[(size_t)c * 64 + ch * 4 + 2];
                float4 ed = e4[(size_t)c * 64 + ch * 4 + 3];
                float ee[16] = {ea.x, ea.y, ea.z, ea.w, eb_.x, eb_.y, eb_.z, eb_.w,
                                ec.x, ec.y, ec.z, ec.w, ed.x, ed.y, ed.z, ed.w};
#pragma unroll
                for (int t = 0; t < 16; ++t) {
#pragma unroll
                    for (int q = 0; q < 4; ++q) {
                        float4 xv = *reinterpret_cast<const float4*>(&xs[t][ch * 16 + q * 4]);
                        // ascending-k single-accumulator chain (bitwise == reference)
                        acc[t] += xv.x * ee[q * 4 + 0];
                        acc[t] += xv.y * ee[q * 4 + 1];
                        acc[t] += xv.z * ee[q * 4 + 2];
                        acc[t] += xv.w * ee[q * 4 + 3];
                    }
                }
            }
#pragma unroll
            for (int t = 0; t < 16; ++t) {
                float tt = As[t] + Bc;            // fl(A+B)
                float s  = tt - 2.0f * acc[t];    // fl(t - 2*dot)
                if (s < m1[t]) { m1[t] = s; i1[t] = c; }  // c ascending per thread
            }
        }
        // reduce: butterfly within wave, then across 4 waves via LDS
#pragma unroll
        for (int off = 1; off <= 32; off <<= 1) {
#pragma unroll
            for (int t = 0; t < 16; ++t) {
                float om = __shfl_xor(m1[t], off, 64);
                int   oi = __shfl_xor(i1[t], off, 64);
                if (om < m1[t] || (om == m1[t] && oi < i1[t])) { m1[t] = om; i1[t] = oi; }
            }
        }
        if (l == 0) {
#pragma unroll
            for (int t = 0; t < 16; ++t) { wmin[wv][t] = m1[t]; widx[wv][t] = i1[t]; }
        }
        __syncthreads();
        if (tid < 16) {
            float bm = wmin[0][tid];
            int   bi = widx[0][tid];
#pragma unroll
            for (int w = 1; w < 4; ++w) {
                float om = wmin[w][tid];
                int   oi = widx[w][tid];
                if (om < bm || (om == bm && oi < bi)) { bm = om; bi = oi; }
            }
            bidx[tid] = bi;
            if (tid < m) outIdx[toks[sb + tid]] = (float)bi;   // clean exact index
        }
        __syncthreads();
        // rewrite z_q rows for this sub-batch
        for (int i = tid; i < m * 64; i += 256) {
            int t = i >> 6, c4 = i & 63;
            zq4[(size_t)toks[sb + t] * 64 + c4] = e4[(size_t)bidx[t] * 64 + c4];
        }
        __syncthreads();   // protect xs/As/bidx before next sub-batch
    }
}

extern "C" void kernel_launch(void* const* d_in, const int* in_sizes, int n_in,
                              void* d_out, int out_size, void* d_ws, size_t ws_size,
                              hipStream_t stream) {
    const float* x   = (const float*)d_in[0];
    const float* emb = (const float*)d_in[1];
    float* out    = (float*)d_out;
    float* zq     = out;
    float* outIdx = out + (size_t)N_TOK * E_DIM;

    char* ws = (char*)d_ws;
    float*  B  = (float*)ws;               // 4 KB
    short8* eb = (short8*)(ws + 4096);     // 512 KB bf16 fragment-order emb

    eprep_kernel<<<128, 256, 0, stream>>>(emb, eb);
    rowsq_kernel<<<N_E / 32, 64, 0, stream>>>(emb, B);
    score_kernel<<<N_TOK / 256, 256, 0, stream>>>(x, emb, eb, B, zq, outIdx);
    recheck_kernel<<<N_TOK / 128, 256, 0, stream>>>(x, emb, B, zq, outIdx);
}

// Round 6
// 1364.966 us; speedup vs baseline: 28.5699x; 3.8099x over previous
//
#include <hip/hip_runtime.h>

// VQ nearest-codebook: x [262144,256] f32, emb [1024,256] f32
// out = concat(z_q [262144*256] f32, min_indices [262144] written as f32)
//
// Round 6: bf16 MFMA scorer with TOP-2 tracking; flag = final (m2-m1 <= THR)
// (R5 bug: sticky flag vs RUNNING min fired on ~100% of tokens -> full recheck).
// Flagged tokens (expected ~10%) re-scored by the twice-validated bitwise
// numpy-f32 chain (pairwise rowsq + ascending-k single-acc fmac + fl(fl(A+B)-2dot)).

constexpr int N_E   = 1024;
constexpr int E_DIM = 256;
constexpr int N_TOK = 262144;
constexpr float THR = 7e-4f;

typedef __attribute__((ext_vector_type(8))) short short8;
typedef __attribute__((ext_vector_type(4))) float f32x4;

// ---------- bitwise-verified helpers (R3/R4/R5) ----------
__device__ __forceinline__ float sqf(float v) {
    float p = v * v;
    asm volatile("" : "+v"(p));
    return p;
}
__device__ __forceinline__ float pwb(const float* b, int n) {
    float U[8];
#pragma unroll
    for (int L = 0; L < 8; ++L) {
        float TL  = (sqf(b[L])     + sqf(b[16 + L])) + (sqf(b[32 + L]) + sqf(b[48 + L]));
        float TL8 = (sqf(b[8 + L]) + sqf(b[24 + L])) + (sqf(b[40 + L]) + sqf(b[56 + L]));
        U[L] = TL + TL8;
    }
    float V0 = U[0] + U[4], V1 = U[1] + U[5], V2 = U[2] + U[6], V3 = U[3] + U[7];
    float res = (V0 + V2) + (V1 + V3);
    for (int i = 64; i < n; ++i) res += sqf(b[i]);
    return res;
}
__device__ __forceinline__ float rowsq_exact(const float* r) {
    return sqf(r[0]) + (pwb(r + 1, 120) + (pwb(r + 121, 64) + pwb(r + 185, 71)));
}
__device__ __forceinline__ unsigned short f2bf(float f) {
    union { float f; unsigned u; } v; v.f = f;
    unsigned r = (v.u + 0x7FFF + ((v.u >> 16) & 1)) >> 16;
    return (unsigned short)r;
}

// ---------- prep: exact ||e_k||^2 ----------
__global__ __launch_bounds__(64) void rowsq_kernel(const float* __restrict__ src,
                                                   float* __restrict__ dst) {
    __shared__ float rs[32][257];
    const int rowBase = blockIdx.x * 32;
    const int tid = threadIdx.x;
    const float4* s4 = reinterpret_cast<const float4*>(src);
    for (int i = tid; i < 32 * 64; i += 64) {
        int rr = i >> 6, c4 = i & 63;
        float4 v = s4[(size_t)(rowBase + rr) * 64 + c4];
        rs[rr][c4 * 4 + 0] = v.x;
        rs[rr][c4 * 4 + 1] = v.y;
        rs[rr][c4 * 4 + 2] = v.z;
        rs[rr][c4 * 4 + 3] = v.w;
    }
    __syncthreads();
    if (tid < 32) dst[rowBase + tid] = rowsq_exact(rs[tid]);
}

// ---------- prep: emb -> bf16 fragment-order [nt][kc][lane] ----------
__global__ __launch_bounds__(256) void eprep_kernel(const float* __restrict__ emb,
                                                    short8* __restrict__ eb) {
    int gid = blockIdx.x * 256 + threadIdx.x;   // 32768
    int lane = gid & 63;
    int kc   = (gid >> 6) & 7;
    int nt   = gid >> 9;
    int cand = nt * 16 + (lane & 15);
    int k0   = kc * 32 + (lane >> 4) * 8;
    const float4* e4 = reinterpret_cast<const float4*>(emb);
    float4 a = e4[(size_t)cand * 64 + k0 / 4];
    float4 b = e4[(size_t)cand * 64 + k0 / 4 + 1];
    short8 o;
    o[0] = (short)f2bf(a.x); o[1] = (short)f2bf(a.y);
    o[2] = (short)f2bf(a.z); o[3] = (short)f2bf(a.w);
    o[4] = (short)f2bf(b.x); o[5] = (short)f2bf(b.y);
    o[6] = (short)f2bf(b.z); o[7] = (short)f2bf(b.w);
    eb[gid] = o;
}

// ---------- MFMA scorer with top-2 (fragment layout verified R4/R5) ----------
__global__ __launch_bounds__(256, 2) void score_kernel(const float* __restrict__ x,
                                                       const float* __restrict__ emb,
                                                       const short8* __restrict__ eb,
                                                       const float* __restrict__ B,
                                                       float* __restrict__ zq,
                                                       float* __restrict__ outIdx) {
    __shared__ int fidx[256];
    const int tid = threadIdx.x;
    const int wv  = tid >> 6;
    const int l   = tid & 63;
    const int col = l & 15;
    const int tokW = blockIdx.x * 256 + wv * 64;
    const float4* x4 = reinterpret_cast<const float4*>(x);

    short8 xf[4][8];
#pragma unroll
    for (int mt = 0; mt < 4; ++mt) {
        int row = tokW + mt * 16 + col;
#pragma unroll
        for (int kc = 0; kc < 8; ++kc) {
            const float4* p = x4 + (size_t)row * 64 + kc * 8 + (l >> 4) * 2;
            float4 a = p[0], b = p[1];
            short8 f;
            f[0] = (short)f2bf(a.x); f[1] = (short)f2bf(a.y);
            f[2] = (short)f2bf(a.z); f[3] = (short)f2bf(a.w);
            f[4] = (short)f2bf(b.x); f[5] = (short)f2bf(b.y);
            f[6] = (short)f2bf(b.z); f[7] = (short)f2bf(b.w);
            xf[mt][kc] = f;
        }
    }

    float m1[16], m2[16];
    int   i1[16];
#pragma unroll
    for (int t = 0; t < 16; ++t) { m1[t] = 3.4e38f; m2[t] = 3.4e38f; i1[t] = 0; }

    for (int nt = 0; nt < 64; ++nt) {
        float Bv = B[nt * 16 + col];
        const short8* ep = eb + nt * 512 + l;
        f32x4 acc0 = {0.f, 0.f, 0.f, 0.f}, acc1 = acc0, acc2 = acc0, acc3 = acc0;
#pragma unroll
        for (int kc = 0; kc < 8; ++kc) {
            short8 ef = ep[kc * 64];
            acc0 = __builtin_amdgcn_mfma_f32_16x16x32_bf16(xf[0][kc], ef, acc0, 0, 0, 0);
            acc1 = __builtin_amdgcn_mfma_f32_16x16x32_bf16(xf[1][kc], ef, acc1, 0, 0, 0);
            acc2 = __builtin_amdgcn_mfma_f32_16x16x32_bf16(xf[2][kc], ef, acc2, 0, 0, 0);
            acc3 = __builtin_amdgcn_mfma_f32_16x16x32_bf16(xf[3][kc], ef, acc3, 0, 0, 0);
        }
        int idx = nt * 16 + col;
#pragma unroll
        for (int mt = 0; mt < 4; ++mt) {
            f32x4 acc = (mt == 0) ? acc0 : (mt == 1) ? acc1 : (mt == 2) ? acc2 : acc3;
#pragma unroll
            for (int r = 0; r < 4; ++r) {
                int t = mt * 4 + r;
                float s = Bv - 2.0f * acc[r];
                bool lt = s < m1[t];
                m2[t] = lt ? m1[t] : fminf(m2[t], s);
                m1[t] = lt ? s : m1[t];
                i1[t] = lt ? idx : i1[t];       // idx ascending -> first occurrence
            }
        }
    }

    // merge top-2 across the 16 candidate-lanes (xor 1,2,4,8); disjoint-set merge
#pragma unroll
    for (int off = 1; off <= 8; off <<= 1) {
#pragma unroll
        for (int t = 0; t < 16; ++t) {
            float om1 = __shfl_xor(m1[t], off, 64);
            int   oi  = __shfl_xor(i1[t], off, 64);
            float om2 = __shfl_xor(m2[t], off, 64);
            float nm2 = fminf(fmaxf(m1[t], om1), fminf(m2[t], om2));
            if (om1 < m1[t] || (om1 == m1[t] && oi < i1[t])) { m1[t] = om1; i1[t] = oi; }
            m2[t] = nm2;
        }
    }

    if (col == 0) {   // 4 leader lanes/wave, each owns row-group l>>4
        int g = l >> 4;
#pragma unroll
        for (int mt = 0; mt < 4; ++mt)
#pragma unroll
            for (int r = 0; r < 4; ++r) {
                int t = mt * 4 + r;
                int token = tokW + mt * 16 + g * 4 + r;
                int fl = (m2[t] - m1[t] <= THR) ? 1 : 0;   // near-tie vs FINAL min
                outIdx[token] = (float)(i1[t] + (fl ? N_E : 0));
                fidx[wv * 64 + mt * 16 + g * 4 + r] = i1[t];
            }
    }
    __syncthreads();

    const float4* e4 = reinterpret_cast<const float4*>(emb);
    float4* zq4 = reinterpret_cast<float4*>(zq);
#pragma unroll
    for (int it = 0; it < 64; ++it) {
        int flat = it * 256 + tid;
        int t = flat >> 6, c = flat & 63;
        zq4[((size_t)blockIdx.x * 256 + t) * 64 + c] = e4[(size_t)fidx[t] * 64 + c];
    }
}

// ---------- batched exact recheck (validated R5 at 100% coverage) ----------
__global__ __launch_bounds__(256) void recheck_kernel(const float* __restrict__ x,
                                                      const float* __restrict__ emb,
                                                      const float* __restrict__ B,
                                                      float* __restrict__ zq,
                                                      float* __restrict__ outIdx) {
    __shared__ float xs[16][257];
    __shared__ float As[16];
    __shared__ int   toks[128];
    __shared__ int   kcount;
    __shared__ float wmin[4][16];
    __shared__ int   widx[4][16];
    __shared__ int   bidx[16];

    const int tid  = threadIdx.x;
    const int wv   = tid >> 6;
    const int l    = tid & 63;
    const int base = blockIdx.x * 128;
    const float4* x4 = reinterpret_cast<const float4*>(x);
    const float4* e4 = reinterpret_cast<const float4*>(emb);
    float4* zq4 = reinterpret_cast<float4*>(zq);

    if (tid == 0) kcount = 0;
    __syncthreads();
    if (tid < 128) {
        float v = outIdx[base + tid];
        if (v >= (float)N_E) {
            int p = atomicAdd(&kcount, 1);
            toks[p] = base + tid;
        }
    }
    __syncthreads();
    const int k = kcount;

    for (int sb = 0; sb < k; sb += 16) {
        const int m = (k - sb < 16) ? (k - sb) : 16;
        for (int i = tid; i < 16 * 64; i += 256) {
            int t = i >> 6, c4 = i & 63;
            float4 v = {0.f, 0.f, 0.f, 0.f};
            if (t < m) v = x4[(size_t)toks[sb + t] * 64 + c4];
            xs[t][c4 * 4 + 0] = v.x;
            xs[t][c4 * 4 + 1] = v.y;
            xs[t][c4 * 4 + 2] = v.z;
            xs[t][c4 * 4 + 3] = v.w;
        }
        __syncthreads();
        if (tid < 16) As[tid] = rowsq_exact(xs[tid]);
        __syncthreads();

        float m1[16];
        int   i1[16];
#pragma unroll
        for (int t = 0; t < 16; ++t) { m1[t] = 3.4e38f; i1[t] = 0; }

        for (int pass = 0; pass < 4; ++pass) {
            const int c = pass * 256 + tid;
            const float Bc = B[c];
            float acc[16];
#pragma unroll
            for (int t = 0; t < 16; ++t) acc[t] = 0.f;
            for (int ch = 0; ch < 16; ++ch) {
                float4 ea = e4[(size_t)c * 64 + ch * 4 + 0];
                float4 eb_ = e4[(size_t)c * 64 + ch * 4 + 1];
                float4 ec = e4[(size_t)c * 64 + ch * 4 + 2];
                float4 ed = e4[(size_t)c * 64 + ch * 4 + 3];
                float ee[16] = {ea.x, ea.y, ea.z, ea.w, eb_.x, eb_.y, eb_.z, eb_.w,
                                ec.x, ec.y, ec.z, ec.w, ed.x, ed.y, ed.z, ed.w};
#pragma unroll
                for (int t = 0; t < 16; ++t) {
#pragma unroll
                    for (int q = 0; q < 4; ++q) {
                        float4 xv = *reinterpret_cast<const float4*>(&xs[t][ch * 16 + q * 4]);
                        acc[t] += xv.x * ee[q * 4 + 0];
                        acc[t] += xv.y * ee[q * 4 + 1];
                        acc[t] += xv.z * ee[q * 4 + 2];
                        acc[t] += xv.w * ee[q * 4 + 3];
                    }
                }
            }
#pragma unroll
            for (int t = 0; t < 16; ++t) {
                float tt = As[t] + Bc;
                float s  = tt - 2.0f * acc[t];
                if (s < m1[t]) { m1[t] = s; i1[t] = c; }
            }
        }
#pragma unroll
        for (int off = 1; off <= 32; off <<= 1) {
#pragma unroll
            for (int t = 0; t < 16; ++t) {
                float om = __shfl_xor(m1[t], off, 64);
                int   oi = __shfl_xor(i1[t], off, 64);
                if (om < m1[t] || (om == m1[t] && oi < i1[t])) { m1[t] = om; i1[t] = oi; }
            }
        }
        if (l == 0) {
#pragma unroll
            for (int t = 0; t < 16; ++t) { wmin[wv][t] = m1[t]; widx[wv][t] = i1[t]; }
        }
        __syncthreads();
        if (tid < 16) {
            float bm = wmin[0][tid];
            int   bi = widx[0][tid];
#pragma unroll
            for (int w = 1; w < 4; ++w) {
                float om = wmin[w][tid];
                int   oi = widx[w][tid];
                if (om < bm || (om == bm && oi < bi)) { bm = om; bi = oi; }
            }
            bidx[tid] = bi;
            if (tid < m) outIdx[toks[sb + tid]] = (float)bi;
        }
        __syncthreads();
        for (int i = tid; i < m * 64; i += 256) {
            int t = i >> 6, c4 = i & 63;
            zq4[(size_t)toks[sb + t] * 64 + c4] = e4[(size_t)bidx[t] * 64 + c4];
        }
        __syncthreads();
    }
}

extern "C" void kernel_launch(void* const* d_in, const int* in_sizes, int n_in,
                              void* d_out, int out_size, void* d_ws, size_t ws_size,
                              hipStream_t stream) {
    const float* x   = (const float*)d_in[0];
    const float* emb = (const float*)d_in[1];
    float* out    = (float*)d_out;
    float* zq     = out;
    float* outIdx = out + (size_t)N_TOK * E_DIM;

    char* ws = (char*)d_ws;
    float*  B  = (float*)ws;               // 4 KB
    short8* eb = (short8*)(ws + 4096);     // 512 KB bf16 fragment-order emb

    eprep_kernel<<<128, 256, 0, stream>>>(emb, eb);
    rowsq_kernel<<<N_E / 32, 64, 0, stream>>>(emb, B);
    score_kernel<<<N_TOK / 256, 256, 0, stream>>>(x, emb, eb, B, zq, outIdx);
    recheck_kernel<<<N_TOK / 128, 256, 0, stream>>>(x, emb, B, zq, outIdx);
}

// Round 7
// 996.761 us; speedup vs baseline: 39.1237x; 1.3694x over previous
//
#include <hip/hip_runtime.h>

// VQ nearest-codebook: x [262144,256] f32, emb [1024,256] f32
// out = concat(z_q [262144*256] f32, min_indices [262144] written as f32)
//
// Round 7: recheck inner-loop restructure: merged candidate passes with
// acc[16 tokens][4 cands] register block, k chunked by 8, aligned ds_read_b128
// (xs stride 260). Bitwise accumulation chain unchanged (ascending-k single
// accumulator per (token,cand) + fl(fl(A+B)-2dot)). Scorer/prep unchanged.

constexpr int N_E   = 1024;
constexpr int E_DIM = 256;
constexpr int N_TOK = 262144;
constexpr float THR = 7e-4f;

typedef __attribute__((ext_vector_type(8))) short short8;
typedef __attribute__((ext_vector_type(4))) float f32x4;

// ---------- bitwise-verified helpers (R3-R6) ----------
__device__ __forceinline__ float sqf(float v) {
    float p = v * v;
    asm volatile("" : "+v"(p));
    return p;
}
__device__ __forceinline__ float pwb(const float* b, int n) {
    float U[8];
#pragma unroll
    for (int L = 0; L < 8; ++L) {
        float TL  = (sqf(b[L])     + sqf(b[16 + L])) + (sqf(b[32 + L]) + sqf(b[48 + L]));
        float TL8 = (sqf(b[8 + L]) + sqf(b[24 + L])) + (sqf(b[40 + L]) + sqf(b[56 + L]));
        U[L] = TL + TL8;
    }
    float V0 = U[0] + U[4], V1 = U[1] + U[5], V2 = U[2] + U[6], V3 = U[3] + U[7];
    float res = (V0 + V2) + (V1 + V3);
    for (int i = 64; i < n; ++i) res += sqf(b[i]);
    return res;
}
__device__ __forceinline__ float rowsq_exact(const float* r) {
    return sqf(r[0]) + (pwb(r + 1, 120) + (pwb(r + 121, 64) + pwb(r + 185, 71)));
}
__device__ __forceinline__ unsigned short f2bf(float f) {
    union { float f; unsigned u; } v; v.f = f;
    unsigned r = (v.u + 0x7FFF + ((v.u >> 16) & 1)) >> 16;
    return (unsigned short)r;
}

// ---------- prep: exact ||e_k||^2 ----------
__global__ __launch_bounds__(64) void rowsq_kernel(const float* __restrict__ src,
                                                   float* __restrict__ dst) {
    __shared__ float rs[32][257];
    const int rowBase = blockIdx.x * 32;
    const int tid = threadIdx.x;
    const float4* s4 = reinterpret_cast<const float4*>(src);
    for (int i = tid; i < 32 * 64; i += 64) {
        int rr = i >> 6, c4 = i & 63;
        float4 v = s4[(size_t)(rowBase + rr) * 64 + c4];
        rs[rr][c4 * 4 + 0] = v.x;
        rs[rr][c4 * 4 + 1] = v.y;
        rs[rr][c4 * 4 + 2] = v.z;
        rs[rr][c4 * 4 + 3] = v.w;
    }
    __syncthreads();
    if (tid < 32) dst[rowBase + tid] = rowsq_exact(rs[tid]);
}

// ---------- prep: emb -> bf16 fragment-order [nt][kc][lane] ----------
__global__ __launch_bounds__(256) void eprep_kernel(const float* __restrict__ emb,
                                                    short8* __restrict__ eb) {
    int gid = blockIdx.x * 256 + threadIdx.x;   // 32768
    int lane = gid & 63;
    int kc   = (gid >> 6) & 7;
    int nt   = gid >> 9;
    int cand = nt * 16 + (lane & 15);
    int k0   = kc * 32 + (lane >> 4) * 8;
    const float4* e4 = reinterpret_cast<const float4*>(emb);
    float4 a = e4[(size_t)cand * 64 + k0 / 4];
    float4 b = e4[(size_t)cand * 64 + k0 / 4 + 1];
    short8 o;
    o[0] = (short)f2bf(a.x); o[1] = (short)f2bf(a.y);
    o[2] = (short)f2bf(a.z); o[3] = (short)f2bf(a.w);
    o[4] = (short)f2bf(b.x); o[5] = (short)f2bf(b.y);
    o[6] = (short)f2bf(b.z); o[7] = (short)f2bf(b.w);
    eb[gid] = o;
}

// ---------- MFMA scorer with top-2 (unchanged from R6) ----------
__global__ __launch_bounds__(256, 2) void score_kernel(const float* __restrict__ x,
                                                       const float* __restrict__ emb,
                                                       const short8* __restrict__ eb,
                                                       const float* __restrict__ B,
                                                       float* __restrict__ zq,
                                                       float* __restrict__ outIdx) {
    __shared__ int fidx[256];
    const int tid = threadIdx.x;
    const int wv  = tid >> 6;
    const int l   = tid & 63;
    const int col = l & 15;
    const int tokW = blockIdx.x * 256 + wv * 64;
    const float4* x4 = reinterpret_cast<const float4*>(x);

    short8 xf[4][8];
#pragma unroll
    for (int mt = 0; mt < 4; ++mt) {
        int row = tokW + mt * 16 + col;
#pragma unroll
        for (int kc = 0; kc < 8; ++kc) {
            const float4* p = x4 + (size_t)row * 64 + kc * 8 + (l >> 4) * 2;
            float4 a = p[0], b = p[1];
            short8 f;
            f[0] = (short)f2bf(a.x); f[1] = (short)f2bf(a.y);
            f[2] = (short)f2bf(a.z); f[3] = (short)f2bf(a.w);
            f[4] = (short)f2bf(b.x); f[5] = (short)f2bf(b.y);
            f[6] = (short)f2bf(b.z); f[7] = (short)f2bf(b.w);
            xf[mt][kc] = f;
        }
    }

    float m1[16], m2[16];
    int   i1[16];
#pragma unroll
    for (int t = 0; t < 16; ++t) { m1[t] = 3.4e38f; m2[t] = 3.4e38f; i1[t] = 0; }

    for (int nt = 0; nt < 64; ++nt) {
        float Bv = B[nt * 16 + col];
        const short8* ep = eb + nt * 512 + l;
        f32x4 acc0 = {0.f, 0.f, 0.f, 0.f}, acc1 = acc0, acc2 = acc0, acc3 = acc0;
#pragma unroll
        for (int kc = 0; kc < 8; ++kc) {
            short8 ef = ep[kc * 64];
            acc0 = __builtin_amdgcn_mfma_f32_16x16x32_bf16(xf[0][kc], ef, acc0, 0, 0, 0);
            acc1 = __builtin_amdgcn_mfma_f32_16x16x32_bf16(xf[1][kc], ef, acc1, 0, 0, 0);
            acc2 = __builtin_amdgcn_mfma_f32_16x16x32_bf16(xf[2][kc], ef, acc2, 0, 0, 0);
            acc3 = __builtin_amdgcn_mfma_f32_16x16x32_bf16(xf[3][kc], ef, acc3, 0, 0, 0);
        }
        int idx = nt * 16 + col;
#pragma unroll
        for (int mt = 0; mt < 4; ++mt) {
            f32x4 acc = (mt == 0) ? acc0 : (mt == 1) ? acc1 : (mt == 2) ? acc2 : acc3;
#pragma unroll
            for (int r = 0; r < 4; ++r) {
                int t = mt * 4 + r;
                float s = Bv - 2.0f * acc[r];
                bool lt = s < m1[t];
                m2[t] = lt ? m1[t] : fminf(m2[t], s);
                m1[t] = lt ? s : m1[t];
                i1[t] = lt ? idx : i1[t];       // idx ascending -> first occurrence
            }
        }
    }

    // top-2 merge across 16 candidate-lanes (disjoint sets at every butterfly step)
#pragma unroll
    for (int off = 1; off <= 8; off <<= 1) {
#pragma unroll
        for (int t = 0; t < 16; ++t) {
            float om1 = __shfl_xor(m1[t], off, 64);
            int   oi  = __shfl_xor(i1[t], off, 64);
            float om2 = __shfl_xor(m2[t], off, 64);
            float nm2 = fminf(fmaxf(m1[t], om1), fminf(m2[t], om2));
            if (om1 < m1[t] || (om1 == m1[t] && oi < i1[t])) { m1[t] = om1; i1[t] = oi; }
            m2[t] = nm2;
        }
    }

    if (col == 0) {
        int g = l >> 4;
#pragma unroll
        for (int mt = 0; mt < 4; ++mt)
#pragma unroll
            for (int r = 0; r < 4; ++r) {
                int t = mt * 4 + r;
                int token = tokW + mt * 16 + g * 4 + r;
                int fl = (m2[t] - m1[t] <= THR) ? 1 : 0;   // near-tie vs FINAL min
                outIdx[token] = (float)(i1[t] + (fl ? N_E : 0));
                fidx[wv * 64 + mt * 16 + g * 4 + r] = i1[t];
            }
    }
    __syncthreads();

    const float4* e4 = reinterpret_cast<const float4*>(emb);
    float4* zq4 = reinterpret_cast<float4*>(zq);
#pragma unroll
    for (int it = 0; it < 64; ++it) {
        int flat = it * 256 + tid;
        int t = flat >> 6, c = flat & 63;
        zq4[((size_t)blockIdx.x * 256 + t) * 64 + c] = e4[(size_t)fidx[t] * 64 + c];
    }
}

// ---------- batched exact recheck, register-blocked acc[16][4] ----------
__global__ __launch_bounds__(256) void recheck_kernel(const float* __restrict__ x,
                                                      const float* __restrict__ emb,
                                                      const float* __restrict__ B,
                                                      float* __restrict__ zq,
                                                      float* __restrict__ outIdx) {
    __shared__ float xs[16][260];       // stride 260: float4-aligned rows
    __shared__ float As[16];
    __shared__ int   toks[128];
    __shared__ int   kcount;
    __shared__ float wmin[4][16];
    __shared__ int   widx[4][16];
    __shared__ int   bidx[16];

    const int tid  = threadIdx.x;
    const int wv   = tid >> 6;
    const int l    = tid & 63;
    const int base = blockIdx.x * 128;
    const float4* x4 = reinterpret_cast<const float4*>(x);
    const float4* e4 = reinterpret_cast<const float4*>(emb);
    float4* zq4 = reinterpret_cast<float4*>(zq);

    if (tid == 0) kcount = 0;
    __syncthreads();
    if (tid < 128) {
        float v = outIdx[base + tid];
        if (v >= (float)N_E) {
            int p = atomicAdd(&kcount, 1);
            toks[p] = base + tid;
        }
    }
    __syncthreads();
    const int k = kcount;
    if (k == 0) return;

    // this thread's 4 candidate rows (c = j*256 + tid), as float4 pointers
    const float4* er[4];
#pragma unroll
    for (int j = 0; j < 4; ++j) er[j] = e4 + (size_t)(j * 256 + tid) * 64;

    for (int sb = 0; sb < k; sb += 16) {
        const int m = (k - sb < 16) ? (k - sb) : 16;
        for (int i = tid; i < 16 * 64; i += 256) {
            int t = i >> 6, c4 = i & 63;
            float4 v = {0.f, 0.f, 0.f, 0.f};
            if (t < m) v = x4[(size_t)toks[sb + t] * 64 + c4];
            *reinterpret_cast<float4*>(&xs[t][c4 * 4]) = v;
        }
        __syncthreads();
        if (tid < 16) As[tid] = rowsq_exact(xs[tid]);
        __syncthreads();

        float acc[16][4];
#pragma unroll
        for (int t = 0; t < 16; ++t)
#pragma unroll
            for (int j = 0; j < 4; ++j) acc[t][j] = 0.f;

        for (int ch = 0; ch < 32; ++ch) {          // 8 k per chunk
            float ee[4][8];
#pragma unroll
            for (int j = 0; j < 4; ++j) {
                float4 a = er[j][ch * 2 + 0];
                float4 b = er[j][ch * 2 + 1];
                ee[j][0] = a.x; ee[j][1] = a.y; ee[j][2] = a.z; ee[j][3] = a.w;
                ee[j][4] = b.x; ee[j][5] = b.y; ee[j][6] = b.z; ee[j][7] = b.w;
            }
#pragma unroll
            for (int t = 0; t < 16; ++t) {
                float4 xa = *reinterpret_cast<const float4*>(&xs[t][ch * 8 + 0]);
                float4 xb = *reinterpret_cast<const float4*>(&xs[t][ch * 8 + 4]);
                float xv[8] = {xa.x, xa.y, xa.z, xa.w, xb.x, xb.y, xb.z, xb.w};
#pragma unroll
                for (int j = 0; j < 4; ++j) {
                    // ascending-k single-accumulator chain (bitwise == reference)
                    acc[t][j] += xv[0] * ee[j][0];
                    acc[t][j] += xv[1] * ee[j][1];
                    acc[t][j] += xv[2] * ee[j][2];
                    acc[t][j] += xv[3] * ee[j][3];
                    acc[t][j] += xv[4] * ee[j][4];
                    acc[t][j] += xv[5] * ee[j][5];
                    acc[t][j] += xv[6] * ee[j][6];
                    acc[t][j] += xv[7] * ee[j][7];
                }
            }
        }

        float m1[16];
        int   i1[16];
#pragma unroll
        for (int t = 0; t < 16; ++t) { m1[t] = 3.4e38f; i1[t] = 0; }
#pragma unroll
        for (int j = 0; j < 4; ++j) {              // j ascending -> c ascending
            int c = j * 256 + tid;
            float Bc = B[c];
#pragma unroll
            for (int t = 0; t < 16; ++t) {
                float tt = As[t] + Bc;             // fl(A+B)
                float s  = tt - 2.0f * acc[t][j];  // fl(t - 2*dot)
                if (s < m1[t]) { m1[t] = s; i1[t] = c; }
            }
        }
#pragma unroll
        for (int off = 1; off <= 32; off <<= 1) {
#pragma unroll
            for (int t = 0; t < 16; ++t) {
                float om = __shfl_xor(m1[t], off, 64);
                int   oi = __shfl_xor(i1[t], off, 64);
                if (om < m1[t] || (om == m1[t] && oi < i1[t])) { m1[t] = om; i1[t] = oi; }
            }
        }
        if (l == 0) {
#pragma unroll
            for (int t = 0; t < 16; ++t) { wmin[wv][t] = m1[t]; widx[wv][t] = i1[t]; }
        }
        __syncthreads();
        if (tid < 16) {
            float bm = wmin[0][tid];
            int   bi = widx[0][tid];
#pragma unroll
            for (int w = 1; w < 4; ++w) {
                float om = wmin[w][tid];
                int   oi = widx[w][tid];
                if (om < bm || (om == bm && oi < bi)) { bm = om; bi = oi; }
            }
            bidx[tid] = bi;
            if (tid < m) outIdx[toks[sb + tid]] = (float)bi;
        }
        __syncthreads();
        for (int i = tid; i < m * 64; i += 256) {
            int t = i >> 6, c4 = i & 63;
            zq4[(size_t)toks[sb + t] * 64 + c4] = e4[(size_t)bidx[t] * 64 + c4];
        }
        __syncthreads();
    }
}

extern "C" void kernel_launch(void* const* d_in, const int* in_sizes, int n_in,
                              void* d_out, int out_size, void* d_ws, size_t ws_size,
                              hipStream_t stream) {
    const float* x   = (const float*)d_in[0];
    const float* emb = (const float*)d_in[1];
    float* out    = (float*)d_out;
    float* zq     = out;
    float* outIdx = out + (size_t)N_TOK * E_DIM;

    char* ws = (char*)d_ws;
    float*  B  = (float*)ws;               // 4 KB
    short8* eb = (short8*)(ws + 4096);     // 512 KB bf16 fragment-order emb

    eprep_kernel<<<128, 256, 0, stream>>>(emb, eb);
    rowsq_kernel<<<N_E / 32, 64, 0, stream>>>(emb, B);
    score_kernel<<<N_TOK / 256, 256, 0, stream>>>(x, emb, eb, B, zq, outIdx);
    recheck_kernel<<<N_TOK / 128, 256, 0, stream>>>(x, emb, B, zq, outIdx);
}

// Round 8
// 615.211 us; speedup vs baseline: 63.3879x; 1.6202x over previous
//
#include <hip/hip_runtime.h>

// VQ nearest-codebook: x [262144,256] f32, emb [1024,256] f32
// out = concat(z_q [262144*256] f32, min_indices [262144] written as f32)
//
// Round 8: THR 7e-4 -> 3e-4 (flag ~5%); recheck driven by a global compacted
// list (ws) with grid-stride filled sub-batches (no padding waste, no tail);
// marker-scan fallback if list exceeds ws capacity. Bitwise exact chain and
// scorer unchanged (validated R3-R7).

constexpr int N_E   = 1024;
constexpr int E_DIM = 256;
constexpr int N_TOK = 262144;
constexpr float THR = 3e-4f;
constexpr int RGRID  = 1024;            // recheck grid
constexpr int RRANGE = N_TOK / RGRID;   // marker-mode scan range (256)

typedef __attribute__((ext_vector_type(8))) short short8;
typedef __attribute__((ext_vector_type(4))) float f32x4;

// ---------- bitwise-verified helpers (R3-R7) ----------
__device__ __forceinline__ float sqf(float v) {
    float p = v * v;
    asm volatile("" : "+v"(p));
    return p;
}
__device__ __forceinline__ float pwb(const float* b, int n) {
    float U[8];
#pragma unroll
    for (int L = 0; L < 8; ++L) {
        float TL  = (sqf(b[L])     + sqf(b[16 + L])) + (sqf(b[32 + L]) + sqf(b[48 + L]));
        float TL8 = (sqf(b[8 + L]) + sqf(b[24 + L])) + (sqf(b[40 + L]) + sqf(b[56 + L]));
        U[L] = TL + TL8;
    }
    float V0 = U[0] + U[4], V1 = U[1] + U[5], V2 = U[2] + U[6], V3 = U[3] + U[7];
    float res = (V0 + V2) + (V1 + V3);
    for (int i = 64; i < n; ++i) res += sqf(b[i]);
    return res;
}
__device__ __forceinline__ float rowsq_exact(const float* r) {
    return sqf(r[0]) + (pwb(r + 1, 120) + (pwb(r + 121, 64) + pwb(r + 185, 71)));
}
__device__ __forceinline__ unsigned short f2bf(float f) {
    union { float f; unsigned u; } v; v.f = f;
    unsigned r = (v.u + 0x7FFF + ((v.u >> 16) & 1)) >> 16;
    return (unsigned short)r;
}

// ---------- prep: exact ||e_k||^2 ----------
__global__ __launch_bounds__(64) void rowsq_kernel(const float* __restrict__ src,
                                                   float* __restrict__ dst) {
    __shared__ float rs[32][257];
    const int rowBase = blockIdx.x * 32;
    const int tid = threadIdx.x;
    const float4* s4 = reinterpret_cast<const float4*>(src);
    for (int i = tid; i < 32 * 64; i += 64) {
        int rr = i >> 6, c4 = i & 63;
        float4 v = s4[(size_t)(rowBase + rr) * 64 + c4];
        rs[rr][c4 * 4 + 0] = v.x;
        rs[rr][c4 * 4 + 1] = v.y;
        rs[rr][c4 * 4 + 2] = v.z;
        rs[rr][c4 * 4 + 3] = v.w;
    }
    __syncthreads();
    if (tid < 32) dst[rowBase + tid] = rowsq_exact(rs[tid]);
}

// ---------- prep: emb -> bf16 fragment-order; zero flag counter ----------
__global__ __launch_bounds__(256) void eprep_kernel(const float* __restrict__ emb,
                                                    short8* __restrict__ eb,
                                                    int* __restrict__ cnt) {
    int gid = blockIdx.x * 256 + threadIdx.x;   // 32768
    if (gid == 0) *cnt = 0;                     // re-zero each launch (graph replays)
    int lane = gid & 63;
    int kc   = (gid >> 6) & 7;
    int nt   = gid >> 9;
    int cand = nt * 16 + (lane & 15);
    int k0   = kc * 32 + (lane >> 4) * 8;
    const float4* e4 = reinterpret_cast<const float4*>(emb);
    float4 a = e4[(size_t)cand * 64 + k0 / 4];
    float4 b = e4[(size_t)cand * 64 + k0 / 4 + 1];
    short8 o;
    o[0] = (short)f2bf(a.x); o[1] = (short)f2bf(a.y);
    o[2] = (short)f2bf(a.z); o[3] = (short)f2bf(a.w);
    o[4] = (short)f2bf(b.x); o[5] = (short)f2bf(b.y);
    o[6] = (short)f2bf(b.z); o[7] = (short)f2bf(b.w);
    eb[gid] = o;
}

// ---------- MFMA scorer with top-2; flagged -> marker + global list ----------
__global__ __launch_bounds__(256, 2) void score_kernel(const float* __restrict__ x,
                                                       const float* __restrict__ emb,
                                                       const short8* __restrict__ eb,
                                                       const float* __restrict__ B,
                                                       float* __restrict__ zq,
                                                       float* __restrict__ outIdx,
                                                       int* __restrict__ cnt,
                                                       int* __restrict__ list,
                                                       int listCap) {
    __shared__ int fidx[256];
    const int tid = threadIdx.x;
    const int wv  = tid >> 6;
    const int l   = tid & 63;
    const int col = l & 15;
    const int tokW = blockIdx.x * 256 + wv * 64;
    const float4* x4 = reinterpret_cast<const float4*>(x);

    short8 xf[4][8];
#pragma unroll
    for (int mt = 0; mt < 4; ++mt) {
        int row = tokW + mt * 16 + col;
#pragma unroll
        for (int kc = 0; kc < 8; ++kc) {
            const float4* p = x4 + (size_t)row * 64 + kc * 8 + (l >> 4) * 2;
            float4 a = p[0], b = p[1];
            short8 f;
            f[0] = (short)f2bf(a.x); f[1] = (short)f2bf(a.y);
            f[2] = (short)f2bf(a.z); f[3] = (short)f2bf(a.w);
            f[4] = (short)f2bf(b.x); f[5] = (short)f2bf(b.y);
            f[6] = (short)f2bf(b.z); f[7] = (short)f2bf(b.w);
            xf[mt][kc] = f;
        }
    }

    float m1[16], m2[16];
    int   i1[16];
#pragma unroll
    for (int t = 0; t < 16; ++t) { m1[t] = 3.4e38f; m2[t] = 3.4e38f; i1[t] = 0; }

    for (int nt = 0; nt < 64; ++nt) {
        float Bv = B[nt * 16 + col];
        const short8* ep = eb + nt * 512 + l;
        f32x4 acc0 = {0.f, 0.f, 0.f, 0.f}, acc1 = acc0, acc2 = acc0, acc3 = acc0;
#pragma unroll
        for (int kc = 0; kc < 8; ++kc) {
            short8 ef = ep[kc * 64];
            acc0 = __builtin_amdgcn_mfma_f32_16x16x32_bf16(xf[0][kc], ef, acc0, 0, 0, 0);
            acc1 = __builtin_amdgcn_mfma_f32_16x16x32_bf16(xf[1][kc], ef, acc1, 0, 0, 0);
            acc2 = __builtin_amdgcn_mfma_f32_16x16x32_bf16(xf[2][kc], ef, acc2, 0, 0, 0);
            acc3 = __builtin_amdgcn_mfma_f32_16x16x32_bf16(xf[3][kc], ef, acc3, 0, 0, 0);
        }
        int idx = nt * 16 + col;
#pragma unroll
        for (int mt = 0; mt < 4; ++mt) {
            f32x4 acc = (mt == 0) ? acc0 : (mt == 1) ? acc1 : (mt == 2) ? acc2 : acc3;
#pragma unroll
            for (int r = 0; r < 4; ++r) {
                int t = mt * 4 + r;
                float s = Bv - 2.0f * acc[r];
                bool lt = s < m1[t];
                m2[t] = lt ? m1[t] : fminf(m2[t], s);
                m1[t] = lt ? s : m1[t];
                i1[t] = lt ? idx : i1[t];       // idx ascending -> first occurrence
            }
        }
    }

    // top-2 merge across the 16 candidate-lanes (disjoint sets per step)
#pragma unroll
    for (int off = 1; off <= 8; off <<= 1) {
#pragma unroll
        for (int t = 0; t < 16; ++t) {
            float om1 = __shfl_xor(m1[t], off, 64);
            int   oi  = __shfl_xor(i1[t], off, 64);
            float om2 = __shfl_xor(m2[t], off, 64);
            float nm2 = fminf(fmaxf(m1[t], om1), fminf(m2[t], om2));
            if (om1 < m1[t] || (om1 == m1[t] && oi < i1[t])) { m1[t] = om1; i1[t] = oi; }
            m2[t] = nm2;
        }
    }

    if (col == 0) {
        int g = l >> 4;
#pragma unroll
        for (int mt = 0; mt < 4; ++mt)
#pragma unroll
            for (int r = 0; r < 4; ++r) {
                int t = mt * 4 + r;
                int token = tokW + mt * 16 + g * 4 + r;
                int fl = (m2[t] - m1[t] <= THR) ? 1 : 0;   // near-tie vs FINAL min
                outIdx[token] = (float)(i1[t] + (fl ? N_E : 0));
                fidx[wv * 64 + mt * 16 + g * 4 + r] = i1[t];
                if (fl) {
                    int p = atomicAdd(cnt, 1);
                    if (p < listCap) list[p] = token;
                }
            }
    }
    __syncthreads();

    const float4* e4 = reinterpret_cast<const float4*>(emb);
    float4* zq4 = reinterpret_cast<float4*>(zq);
#pragma unroll
    for (int it = 0; it < 64; ++it) {
        int flat = it * 256 + tid;
        int t = flat >> 6, c = flat & 63;
        zq4[((size_t)blockIdx.x * 256 + t) * 64 + c] = e4[(size_t)fidx[t] * 64 + c];
    }
}

// ---------- one exact sub-batch (validated inner loop from R7) ----------
__device__ __forceinline__ void process_batch(const float4* x4, const float4* e4,
                                              const float* B, float4* zq4,
                                              float* outIdx,
                                              const int* toks, int m,
                                              float (*xs)[260], float* As,
                                              float (*wmin)[16], int (*widx)[16],
                                              int* bidx, int tid, int wv, int l) {
    for (int i = tid; i < 16 * 64; i += 256) {
        int t = i >> 6, c4 = i & 63;
        float4 v = {0.f, 0.f, 0.f, 0.f};
        if (t < m) v = x4[(size_t)toks[t] * 64 + c4];
        *reinterpret_cast<float4*>(&xs[t][c4 * 4]) = v;
    }
    __syncthreads();
    if (tid < 16) As[tid] = rowsq_exact(xs[tid]);
    __syncthreads();

    const float4* er[4];
#pragma unroll
    for (int j = 0; j < 4; ++j) er[j] = e4 + (size_t)(j * 256 + tid) * 64;

    float acc[16][4];
#pragma unroll
    for (int t = 0; t < 16; ++t)
#pragma unroll
        for (int j = 0; j < 4; ++j) acc[t][j] = 0.f;

    for (int ch = 0; ch < 32; ++ch) {          // 8 k per chunk
        float ee[4][8];
#pragma unroll
        for (int j = 0; j < 4; ++j) {
            float4 a = er[j][ch * 2 + 0];
            float4 b = er[j][ch * 2 + 1];
            ee[j][0] = a.x; ee[j][1] = a.y; ee[j][2] = a.z; ee[j][3] = a.w;
            ee[j][4] = b.x; ee[j][5] = b.y; ee[j][6] = b.z; ee[j][7] = b.w;
        }
#pragma unroll
        for (int t = 0; t < 16; ++t) {
            float4 xa = *reinterpret_cast<const float4*>(&xs[t][ch * 8 + 0]);
            float4 xb = *reinterpret_cast<const float4*>(&xs[t][ch * 8 + 4]);
            float xv[8] = {xa.x, xa.y, xa.z, xa.w, xb.x, xb.y, xb.z, xb.w};
#pragma unroll
            for (int j = 0; j < 4; ++j) {
                // ascending-k single-accumulator chain (bitwise == reference)
                acc[t][j] += xv[0] * ee[j][0];
                acc[t][j] += xv[1] * ee[j][1];
                acc[t][j] += xv[2] * ee[j][2];
                acc[t][j] += xv[3] * ee[j][3];
                acc[t][j] += xv[4] * ee[j][4];
                acc[t][j] += xv[5] * ee[j][5];
                acc[t][j] += xv[6] * ee[j][6];
                acc[t][j] += xv[7] * ee[j][7];
            }
        }
    }

    float m1[16];
    int   i1[16];
#pragma unroll
    for (int t = 0; t < 16; ++t) { m1[t] = 3.4e38f; i1[t] = 0; }
#pragma unroll
    for (int j = 0; j < 4; ++j) {              // j ascending -> c ascending
        int c = j * 256 + tid;
        float Bc = B[c];
#pragma unroll
        for (int t = 0; t < 16; ++t) {
            float tt = As[t] + Bc;             // fl(A+B)
            float s  = tt - 2.0f * acc[t][j];  // fl(t - 2*dot)
            if (s < m1[t]) { m1[t] = s; i1[t] = c; }
        }
    }
#pragma unroll
    for (int off = 1; off <= 32; off <<= 1) {
#pragma unroll
        for (int t = 0; t < 16; ++t) {
            float om = __shfl_xor(m1[t], off, 64);
            int   oi = __shfl_xor(i1[t], off, 64);
            if (om < m1[t] || (om == m1[t] && oi < i1[t])) { m1[t] = om; i1[t] = oi; }
        }
    }
    if (l == 0) {
#pragma unroll
        for (int t = 0; t < 16; ++t) { wmin[wv][t] = m1[t]; widx[wv][t] = i1[t]; }
    }
    __syncthreads();
    if (tid < 16) {
        float bm = wmin[0][tid];
        int   bi = widx[0][tid];
#pragma unroll
        for (int w = 1; w < 4; ++w) {
            float om = wmin[w][tid];
            int   oi = widx[w][tid];
            if (om < bm || (om == bm && oi < bi)) { bm = om; bi = oi; }
        }
        bidx[tid] = bi;
        if (tid < m) outIdx[toks[tid]] = (float)bi;
    }
    __syncthreads();
    for (int i = tid; i < m * 64; i += 256) {
        int t = i >> 6, c4 = i & 63;
        zq4[(size_t)toks[t] * 64 + c4] = e4[(size_t)bidx[t] * 64 + c4];
    }
    __syncthreads();
}

// ---------- recheck: list-driven (balanced) or marker-scan fallback ----------
__global__ __launch_bounds__(256) void recheck_kernel(const float* __restrict__ x,
                                                      const float* __restrict__ emb,
                                                      const float* __restrict__ B,
                                                      float* __restrict__ zq,
                                                      float* __restrict__ outIdx,
                                                      const int* __restrict__ cnt,
                                                      const int* __restrict__ list,
                                                      int listCap) {
    __shared__ float xs[16][260];
    __shared__ float As[16];
    __shared__ float wmin[4][16];
    __shared__ int   widx[4][16];
    __shared__ int   bidx[16];
    __shared__ int   lt[RRANGE];
    __shared__ int   kcount;

    const int tid = threadIdx.x;
    const int wv  = tid >> 6;
    const int l   = tid & 63;
    const float4* x4 = reinterpret_cast<const float4*>(x);
    const float4* e4 = reinterpret_cast<const float4*>(emb);
    float4* zq4 = reinterpret_cast<float4*>(zq);

    const int n = *cnt;
    if (n == 0) return;

    if (n <= listCap) {
        // balanced mode: grid-stride over filled sub-batches of 16
        const int nsb = (n + 15) >> 4;
        for (int sb = blockIdx.x; sb < nsb; sb += gridDim.x) {
            const int m = (n - sb * 16 < 16) ? (n - sb * 16) : 16;
            if (tid < m) lt[tid] = list[sb * 16 + tid];
            __syncthreads();
            process_batch(x4, e4, B, zq4, outIdx, lt, m,
                          xs, As, wmin, widx, bidx, tid, wv, l);
        }
    } else {
        // fallback: scan my token range for markers (always correct)
        const int base = blockIdx.x * RRANGE;
        if (tid == 0) kcount = 0;
        __syncthreads();
        for (int i = tid; i < RRANGE; i += 256) {
            float v = outIdx[base + i];
            if (v >= (float)N_E) {
                int p = atomicAdd(&kcount, 1);
                lt[p] = base + i;
            }
        }
        __syncthreads();
        const int k = kcount;
        for (int sb = 0; sb < k; sb += 16) {
            const int m = (k - sb < 16) ? (k - sb) : 16;
            process_batch(x4, e4, B, zq4, outIdx, lt + sb, m,
                          xs, As, wmin, widx, bidx, tid, wv, l);
        }
    }
}

extern "C" void kernel_launch(void* const* d_in, const int* in_sizes, int n_in,
                              void* d_out, int out_size, void* d_ws, size_t ws_size,
                              hipStream_t stream) {
    const float* x   = (const float*)d_in[0];
    const float* emb = (const float*)d_in[1];
    float* out    = (float*)d_out;
    float* zq     = out;
    float* outIdx = out + (size_t)N_TOK * E_DIM;

    char* ws = (char*)d_ws;
    int*    cnt  = (int*)ws;                    // @0
    float*  B    = (float*)(ws + 4096);         // 4 KB
    short8* eb   = (short8*)(ws + 8192);        // 512 KB bf16 fragment-order emb
    int*    list = (int*)(ws + 8192 + 524288);
    long avail = (long)ws_size - (8192 + 524288);
    int listCap = avail > 0 ? (int)(avail / 4) : 0;
    if (listCap > N_TOK) listCap = N_TOK;

    eprep_kernel<<<128, 256, 0, stream>>>(emb, eb, cnt);
    rowsq_kernel<<<N_E / 32, 64, 0, stream>>>(emb, B);
    score_kernel<<<N_TOK / 256, 256, 0, stream>>>(x, emb, eb, B, zq, outIdx, cnt, list, listCap);
    recheck_kernel<<<RGRID, 256, 0, stream>>>(x, emb, B, zq, outIdx, cnt, list, listCap);
}